// Round 1
// baseline (15426.807 us; speedup 1.0000x reference)
//
#include <hip/hip_runtime.h>
#include <math.h>

#define SEQn 4096
#define EMBn 1024
#define Hn   512
#define G4n  2048
#define NTAGn 34
#define START_TAG 32
#define STOP_TAG 33
#define NEGV (-10000.0f)

// ---------------------------------------------------------------------------
// Kernel 1: xg = embed[sent] @ W_ih^T + (b_ih + b_hh)
// C[m][n] = sum_k embed[sent[m]][k] * W[n][k] + bias(n)
// grid (64, 32), block 256, 64x64 tile, K-tile 32, fp32
// ---------------------------------------------------------------------------
__global__ __launch_bounds__(256) void xg_gemm_kernel(
    const int* __restrict__ sent, const float* __restrict__ embed,
    const float* __restrict__ W, const float* __restrict__ bia,
    const float* __restrict__ bib, float* __restrict__ C)
{
  __shared__ __align__(16) float As[32][68];
  __shared__ __align__(16) float Bs[32][68];
  const int tid = threadIdx.x;
  const int tx = tid & 15, ty = tid >> 4;
  const int m0 = blockIdx.x * 64, n0 = blockIdx.y * 64;
  const int lr = tid >> 3, lc = tid & 7;

  const float* arow0 = embed + (size_t)sent[m0 + lr] * EMBn;
  const float* arow1 = embed + (size_t)sent[m0 + 32 + lr] * EMBn;
  const float* brow0 = W + (size_t)(n0 + lr) * EMBn;
  const float* brow1 = W + (size_t)(n0 + 32 + lr) * EMBn;

  float acc[4][4] = {};

  for (int kt = 0; kt < EMBn; kt += 32) {
    float4 a0 = *(const float4*)(arow0 + kt + lc * 4);
    float4 a1 = *(const float4*)(arow1 + kt + lc * 4);
    float4 b0 = *(const float4*)(brow0 + kt + lc * 4);
    float4 b1 = *(const float4*)(brow1 + kt + lc * 4);
    __syncthreads();
    As[lc*4+0][lr] = a0.x; As[lc*4+1][lr] = a0.y; As[lc*4+2][lr] = a0.z; As[lc*4+3][lr] = a0.w;
    As[lc*4+0][32+lr] = a1.x; As[lc*4+1][32+lr] = a1.y; As[lc*4+2][32+lr] = a1.z; As[lc*4+3][32+lr] = a1.w;
    Bs[lc*4+0][lr] = b0.x; Bs[lc*4+1][lr] = b0.y; Bs[lc*4+2][lr] = b0.z; Bs[lc*4+3][lr] = b0.w;
    Bs[lc*4+0][32+lr] = b1.x; Bs[lc*4+1][32+lr] = b1.y; Bs[lc*4+2][32+lr] = b1.z; Bs[lc*4+3][32+lr] = b1.w;
    __syncthreads();
#pragma unroll
    for (int kk = 0; kk < 32; ++kk) {
      float4 av = *(const float4*)&As[kk][ty * 4];
      float4 bv = *(const float4*)&Bs[kk][tx * 4];
      acc[0][0] += av.x * bv.x; acc[0][1] += av.x * bv.y; acc[0][2] += av.x * bv.z; acc[0][3] += av.x * bv.w;
      acc[1][0] += av.y * bv.x; acc[1][1] += av.y * bv.y; acc[1][2] += av.y * bv.z; acc[1][3] += av.y * bv.w;
      acc[2][0] += av.z * bv.x; acc[2][1] += av.z * bv.y; acc[2][2] += av.z * bv.z; acc[2][3] += av.z * bv.w;
      acc[3][0] += av.w * bv.x; acc[3][1] += av.w * bv.y; acc[3][2] += av.w * bv.z; acc[3][3] += av.w * bv.w;
    }
  }
#pragma unroll
  for (int i = 0; i < 4; ++i) {
    int m = m0 + ty * 4 + i;
#pragma unroll
    for (int j = 0; j < 4; ++j) {
      int n = n0 + tx * 4 + j;
      C[(size_t)m * G4n + n] = acc[i][j] + bia[n] + bib[n];
    }
  }
}

// ---------------------------------------------------------------------------
// Kernel 2: persistent bidirectional LSTM.
// 32 blocks x 1024 threads. Blocks 0..15 forward, 16..31 backward.
// Each block owns 32 h-elements -> 128 gate rows; W_hh slice in registers
// (64 VGPRs/thread: thread = (row r = t>>3, segment seg = t&7 of 64 k)).
// h exchanged via global (double-buffered) + device-scope atomic barrier.
// ---------------------------------------------------------------------------
__global__ __launch_bounds__(1024) void lstm_kernel(
    const float* __restrict__ xg_f, const float* __restrict__ xg_b,
    const float* __restrict__ w_hh_f, const float* __restrict__ w_hh_b,
    const float* __restrict__ h0, const float* __restrict__ c0,
    float* __restrict__ hs, float* __restrict__ hbuf, unsigned* __restrict__ bar)
{
  const int b = blockIdx.x;
  const int dir = b >> 4;
  const int blk = b & 15;
  const int hbase = blk * 32;
  const float* W  = dir ? w_hh_b : w_hh_f;
  const float* xg = dir ? xg_b : xg_f;
  unsigned* ctr = bar + dir * 32;   // 128B apart

  const int t   = threadIdx.x;
  const int r   = t >> 3;          // 0..127 local gate row
  const int seg = t & 7;           // 64-wide k segment
  const int gi  = r >> 5;          // gate index (uniform per wave)
  const int idx = r & 31;
  const int R   = gi * Hn + hbase + idx;   // global gate row in [0,2048)

  // W slice, float4-permuted so LDS reads are bank-conflict-free:
  // wreg[jj] holds k-quad q = (seg+jj)&15 of this thread's 64-wide segment.
  float4 wreg[16];
  {
    const float* wrow = W + (size_t)R * Hn + seg * 64;
#pragma unroll
    for (int jj = 0; jj < 16; ++jj) {
      int q = (seg + jj) & 15;
      wreg[jj] = *(const float4*)(wrow + q * 4);
    }
  }

  __shared__ __align__(16) float h_lds[Hn];
  __shared__ float gact[128];

  float c_reg = 0.f;
  if (t < 32) c_reg = c0[dir * Hn + hbase + t];

  for (int step = 0; step < SEQn; ++step) {
    const int s = dir ? (SEQn - 1 - step) : step;

    // prefetch this step's xg value (used after the dot product)
    float xgv = 0.f;
    if (seg == 0) xgv = xg[(size_t)s * G4n + R];

    // load current h into LDS (double-buffered global h)
    if (t < Hn) {
      h_lds[t] = (step == 0) ? h0[dir * Hn + t]
                             : hbuf[((step & 1) * 2 + dir) * Hn + t];
    }
    __syncthreads();

    // 64-wide partial dot, bank-conflict-free rotation
    float sum = 0.f;
    const float* hseg = h_lds + seg * 64;
#pragma unroll
    for (int jj = 0; jj < 16; ++jj) {
      int q = (seg + jj) & 15;
      float4 hv = *(const float4*)(hseg + q * 4);
      float4 wv = wreg[jj];
      sum += wv.x * hv.x + wv.y * hv.y + wv.z * hv.z + wv.w * hv.w;
    }
    sum += __shfl_xor(sum, 1);
    sum += __shfl_xor(sum, 2);
    sum += __shfl_xor(sum, 4);

    if (seg == 0) {
      float g = sum + xgv;
      float a = (gi == 2) ? tanhf(g) : 1.f / (1.f + expf(-g));
      gact[r] = a;
    }
    __syncthreads();

    if (t < 32) {
      float iv = gact[t], fv = gact[32 + t], gv = gact[64 + t], ov = gact[96 + t];
      float c = fv * c_reg + iv * gv;
      c_reg = c;
      float h = ov * tanhf(c);
      hbuf[(((step + 1) & 1) * 2 + dir) * Hn + hbase + t] = h;
      hs[(size_t)s * 1024 + dir * Hn + hbase + t] = h;
    }
    __syncthreads();

    if (step < SEQn - 1) {
      if (t == 0) {
        __threadfence();
        atomicAdd(ctr, 1u);
        unsigned target = 16u * (unsigned)(step + 1);
        while (atomicAdd(ctr, 0u) < target) __builtin_amdgcn_s_sleep(2);
        __threadfence();
      }
      __syncthreads();
    }
  }
}

// ---------------------------------------------------------------------------
// Kernel 3: feats = [hs_f|hs_b] @ W_out^T + b_out     (4096 x 34)
// one 64-lane wave per sequence position
// ---------------------------------------------------------------------------
__global__ __launch_bounds__(64) void feats_kernel(
    const float* __restrict__ hs, const float* __restrict__ W_out,
    const float* __restrict__ b_out, float* __restrict__ feats)
{
  const int tq = blockIdx.x;
  const int lane = threadIdx.x;
  const float* hrow = hs + (size_t)tq * 1024;
  float4 hv[4];
#pragma unroll
  for (int i = 0; i < 4; ++i) hv[i] = *(const float4*)(hrow + lane * 16 + i * 4);

  for (int tag = 0; tag < NTAGn; ++tag) {
    const float* wrow = W_out + (size_t)tag * 1024 + lane * 16;
    float s = 0.f;
#pragma unroll
    for (int i = 0; i < 4; ++i) {
      float4 wv = *(const float4*)(wrow + i * 4);
      s += hv[i].x * wv.x + hv[i].y * wv.y + hv[i].z * wv.z + hv[i].w * wv.w;
    }
#pragma unroll
    for (int off = 32; off; off >>= 1) s += __shfl_xor(s, off);
    if (lane == 0) feats[(size_t)tq * NTAGn + tag] = s + b_out[tag];
  }
}

// ---------------------------------------------------------------------------
// Kernel 4: Viterbi forward + backtrack. Single wave; lane = tag.
// fv in LDS (padded to 36), transition row in registers,
// backpointers in 139 KB dynamic LDS for fast backtrack.
// ---------------------------------------------------------------------------
__global__ __launch_bounds__(64) void viterbi_kernel(
    const float* __restrict__ feats, const float* __restrict__ logT,
    float* __restrict__ out)
{
  extern __shared__ unsigned char bp[];   // SEQn * NTAGn bytes
  __shared__ float fv_s[36];
  __shared__ float red[36];
  const int lane = threadIdx.x;
  const bool active = lane < NTAGn;

  float Trow[36];
  if (active) {
#pragma unroll
    for (int j = 0; j < NTAGn; ++j) Trow[j] = logT[lane * NTAGn + j];
    Trow[34] = NEGV; Trow[35] = NEGV;
    fv_s[lane] = (lane == START_TAG) ? 0.f : NEGV;
  }
  if (lane == 0) { fv_s[34] = NEGV; fv_s[35] = NEGV; }
  __syncthreads();

  float ft = active ? feats[lane] : 0.f;
  for (int tv = 0; tv < SEQn; ++tv) {
    float best = -3.4e38f; int bj = 0;
    float ftn = 0.f;
    if (active) {
      float sc[36];
#pragma unroll
      for (int q = 0; q < 9; ++q) {
        float4 f4 = *(const float4*)&fv_s[q * 4];
        sc[q*4+0] = f4.x + Trow[q*4+0];
        sc[q*4+1] = f4.y + Trow[q*4+1];
        sc[q*4+2] = f4.z + Trow[q*4+2];
        sc[q*4+3] = f4.w + Trow[q*4+3];
      }
      best = sc[0];
#pragma unroll
      for (int j = 1; j < 36; ++j) { if (sc[j] > best) { best = sc[j]; bj = j; } }
      if (tv + 1 < SEQn) ftn = feats[(size_t)(tv + 1) * NTAGn + lane];
    }
    // single wave: all fv reads above complete (in-order DS) before the store
    if (active) {
      fv_s[lane] = best + ft;
      bp[tv * NTAGn + lane] = (unsigned char)bj;
    }
    __threadfence_block();
    ft = ftn;
  }

  if (active) red[lane] = fv_s[lane] + logT[STOP_TAG * NTAGn + lane];
  __threadfence_block();
  __syncthreads();
  if (lane == 0) {
    float bestv = -3.4e38f; int bi = 0;
#pragma unroll
    for (int i = 0; i < NTAGn; ++i) { float v = red[i]; if (v > bestv) { bestv = v; bi = i; } }
    out[0] = bestv;
    int tag = bi;
    out[1 + SEQn - 1] = (float)tag;
    for (int tv = SEQn - 1; tv >= 1; --tv) {
      tag = bp[tv * NTAGn + tag];
      out[tv] = (float)tag;   // out[1 + (tv-1)]
    }
  }
}

// ---------------------------------------------------------------------------
extern "C" void kernel_launch(void* const* d_in, const int* in_sizes, int n_in,
                              void* d_out, int out_size, void* d_ws, size_t ws_size,
                              hipStream_t stream) {
  const int*   sent   = (const int*)d_in[0];
  const float* embed  = (const float*)d_in[1];
  const float* w_ih_f = (const float*)d_in[2];
  const float* w_hh_f = (const float*)d_in[3];
  const float* b_ih_f = (const float*)d_in[4];
  const float* b_hh_f = (const float*)d_in[5];
  const float* w_ih_b = (const float*)d_in[6];
  const float* w_hh_b = (const float*)d_in[7];
  const float* b_ih_b = (const float*)d_in[8];
  const float* b_hh_b = (const float*)d_in[9];
  const float* W_out  = (const float*)d_in[10];
  const float* b_out  = (const float*)d_in[11];
  const float* logT   = (const float*)d_in[12];
  const float* h0     = (const float*)d_in[13];
  const float* c0     = (const float*)d_in[14];
  float* out = (float*)d_out;

  char* ws = (char*)d_ws;
  size_t off = 0;
  float* xg_f  = (float*)(ws + off); off += (size_t)SEQn * G4n * 4;
  float* xg_b  = (float*)(ws + off); off += (size_t)SEQn * G4n * 4;
  float* hs    = (float*)(ws + off); off += (size_t)SEQn * 1024 * 4;
  float* feats = (float*)(ws + off); off += (size_t)SEQn * NTAGn * 4;
  float* hbuf  = (float*)(ws + off); off += 2 * 2 * Hn * 4;
  unsigned* bar = (unsigned*)(ws + off); off += 256;

  hipMemsetAsync(bar, 0, 256, stream);

  dim3 gg(SEQn / 64, G4n / 64);
  xg_gemm_kernel<<<gg, 256, 0, stream>>>(sent, embed, w_ih_f, b_ih_f, b_hh_f, xg_f);
  xg_gemm_kernel<<<gg, 256, 0, stream>>>(sent, embed, w_ih_b, b_ih_b, b_hh_b, xg_b);

  lstm_kernel<<<32, 1024, 0, stream>>>(xg_f, xg_b, w_hh_f, w_hh_b, h0, c0, hs, hbuf, bar);

  feats_kernel<<<SEQn, 64, 0, stream>>>(hs, W_out, b_out, feats);

  static const int dyn_lds = SEQn * NTAGn;   // 139264 bytes
  hipFuncSetAttribute((const void*)viterbi_kernel,
                      hipFuncAttributeMaxDynamicSharedMemorySize, dyn_lds);
  viterbi_kernel<<<1, 64, dyn_lds, stream>>>(feats, logT, out);
}

// Round 2
// 13599.927 us; speedup vs baseline: 1.1343x; 1.1343x over previous
//
#include <hip/hip_runtime.h>
#include <math.h>

#define SEQn 4096
#define EMBn 1024
#define Hn   512
#define G4n  2048
#define NTAGn 34
#define START_TAG 32
#define STOP_TAG 33
#define NEGV (-10000.0f)

// ---------------------------------------------------------------------------
// Kernel 1: xg = embed[sent] @ W_ih^T + (b_ih + b_hh)
// ---------------------------------------------------------------------------
__global__ __launch_bounds__(256) void xg_gemm_kernel(
    const int* __restrict__ sent, const float* __restrict__ embed,
    const float* __restrict__ W, const float* __restrict__ bia,
    const float* __restrict__ bib, float* __restrict__ C)
{
  __shared__ __align__(16) float As[32][68];
  __shared__ __align__(16) float Bs[32][68];
  const int tid = threadIdx.x;
  const int tx = tid & 15, ty = tid >> 4;
  const int m0 = blockIdx.x * 64, n0 = blockIdx.y * 64;
  const int lr = tid >> 3, lc = tid & 7;

  const float* arow0 = embed + (size_t)sent[m0 + lr] * EMBn;
  const float* arow1 = embed + (size_t)sent[m0 + 32 + lr] * EMBn;
  const float* brow0 = W + (size_t)(n0 + lr) * EMBn;
  const float* brow1 = W + (size_t)(n0 + 32 + lr) * EMBn;

  float acc[4][4] = {};

  for (int kt = 0; kt < EMBn; kt += 32) {
    float4 a0 = *(const float4*)(arow0 + kt + lc * 4);
    float4 a1 = *(const float4*)(arow1 + kt + lc * 4);
    float4 b0 = *(const float4*)(brow0 + kt + lc * 4);
    float4 b1 = *(const float4*)(brow1 + kt + lc * 4);
    __syncthreads();
    As[lc*4+0][lr] = a0.x; As[lc*4+1][lr] = a0.y; As[lc*4+2][lr] = a0.z; As[lc*4+3][lr] = a0.w;
    As[lc*4+0][32+lr] = a1.x; As[lc*4+1][32+lr] = a1.y; As[lc*4+2][32+lr] = a1.z; As[lc*4+3][32+lr] = a1.w;
    Bs[lc*4+0][lr] = b0.x; Bs[lc*4+1][lr] = b0.y; Bs[lc*4+2][lr] = b0.z; Bs[lc*4+3][lr] = b0.w;
    Bs[lc*4+0][32+lr] = b1.x; Bs[lc*4+1][32+lr] = b1.y; Bs[lc*4+2][32+lr] = b1.z; Bs[lc*4+3][32+lr] = b1.w;
    __syncthreads();
#pragma unroll
    for (int kk = 0; kk < 32; ++kk) {
      float4 av = *(const float4*)&As[kk][ty * 4];
      float4 bv = *(const float4*)&Bs[kk][tx * 4];
      acc[0][0] += av.x * bv.x; acc[0][1] += av.x * bv.y; acc[0][2] += av.x * bv.z; acc[0][3] += av.x * bv.w;
      acc[1][0] += av.y * bv.x; acc[1][1] += av.y * bv.y; acc[1][2] += av.y * bv.z; acc[1][3] += av.y * bv.w;
      acc[2][0] += av.z * bv.x; acc[2][1] += av.z * bv.y; acc[2][2] += av.z * bv.z; acc[2][3] += av.z * bv.w;
      acc[3][0] += av.w * bv.x; acc[3][1] += av.w * bv.y; acc[3][2] += av.w * bv.z; acc[3][3] += av.w * bv.w;
    }
  }
#pragma unroll
  for (int i = 0; i < 4; ++i) {
    int m = m0 + ty * 4 + i;
#pragma unroll
    for (int j = 0; j < 4; ++j) {
      int n = n0 + tx * 4 + j;
      C[(size_t)m * G4n + n] = acc[i][j] + bia[n] + bib[n];
    }
  }
}

// ---------------------------------------------------------------------------
// Kernel 2: persistent bidirectional LSTM, v2.
// 32 blocks x 1024 threads; blocks 0..15 forward, 16..31 backward.
// Block owns 32 h-outputs (128 gate rows). Wave w owns h-segment
// [32w, 32w+32) -> LDS reads are wave-uniform broadcasts (free).
// Lane l owns local gate rows {l, l+64}: W slice = 16 float4 regs.
// Cross-wave reduce via padded LDS. Barrier: release-RMW arrive +
// acquire-LOAD polling (no RMW spin contention).
// ---------------------------------------------------------------------------
__global__ __launch_bounds__(1024) void lstm_kernel(
    const float* __restrict__ xg_f, const float* __restrict__ xg_b,
    const float* __restrict__ w_hh_f, const float* __restrict__ w_hh_b,
    const float* __restrict__ h0, const float* __restrict__ c0,
    float* __restrict__ hs, float* __restrict__ hbuf, unsigned* __restrict__ bar)
{
  const int b = blockIdx.x;
  const int dir = b >> 4;
  const int blk = b & 15;
  const int hbase = blk * 32;
  const float* W  = dir ? w_hh_b : w_hh_f;
  const float* xg = dir ? xg_b : xg_f;
  unsigned* ctr = bar + dir * 64;   // 256B apart

  const int t = threadIdx.x;
  const int w = t >> 6;       // wave id 0..15 -> h segment [w*32, w*32+32)
  const int l = t & 63;       // lane -> local rows l, l+64

  // local row r: gi = r>>5 (gate), idx = r&31; global gate row = gi*512+hbase+idx
  const int R0 = ((l) >> 5) * Hn + hbase + (l & 31);
  const int R1 = ((l + 64) >> 5) * Hn + hbase + ((l + 64) & 31);
  float4 wreg[16];
  {
    const float* wr0 = W + (size_t)R0 * Hn + w * 32;
    const float* wr1 = W + (size_t)R1 * Hn + w * 32;
#pragma unroll
    for (int jj = 0; jj < 8; ++jj) {
      wreg[jj]     = *(const float4*)(wr0 + jj * 4);
      wreg[8 + jj] = *(const float4*)(wr1 + jj * 4);
    }
  }

  __shared__ __align__(16) float h_lds[Hn];
  __shared__ float part[16 * 130];   // [wave][row], pad 130 -> 2-way banks
  __shared__ float gact[128];

  float c_reg = 0.f;
  if (t < 32) c_reg = c0[dir * Hn + hbase + t];

  for (int step = 0; step < SEQn; ++step) {
    const int s = dir ? (SEQn - 1 - step) : step;

    // prefetch this step's xg (hidden under the poll)
    float xgv = 0.f;
    if (t < 128) {
      int R = (t >> 5) * Hn + hbase + (t & 31);
      xgv = xg[(size_t)s * G4n + R];
    }

    if (step > 0) {
      if (t == 0) {
        unsigned target = 16u * (unsigned)step;
        while (__hip_atomic_load(ctr, __ATOMIC_ACQUIRE, __HIP_MEMORY_SCOPE_AGENT) < target)
          __builtin_amdgcn_s_sleep(1);
        __builtin_amdgcn_fence(__ATOMIC_ACQUIRE, "agent");
      }
      __syncthreads();
    }

    // load h into LDS (128 float4 lanes)
    if (t < 128) {
      float4 hv = (step == 0)
        ? *(const float4*)(h0 + dir * Hn + t * 4)
        : *(const float4*)(hbuf + ((step & 1) * 2 + dir) * Hn + t * 4);
      *(float4*)&h_lds[t * 4] = hv;
    }
    __syncthreads();

    // dot: wave-uniform h segment (broadcast reads), 2 rows per lane
    float a0 = 0.f, a1 = 0.f;
    const float* hseg = h_lds + w * 32;
#pragma unroll
    for (int jj = 0; jj < 8; ++jj) {
      float4 hv = *(const float4*)(hseg + jj * 4);
      float4 wa = wreg[jj], wb = wreg[8 + jj];
      a0 += wa.x * hv.x + wa.y * hv.y + wa.z * hv.z + wa.w * hv.w;
      a1 += wb.x * hv.x + wb.y * hv.y + wb.z * hv.z + wb.w * hv.w;
    }
    part[w * 130 + l] = a0;
    part[w * 130 + 64 + l] = a1;
    __syncthreads();

    if (t < 128) {
      float sum = 0.f;
#pragma unroll
      for (int ww = 0; ww < 16; ++ww) sum += part[ww * 130 + t];
      float g = sum + xgv;
      gact[t] = ((t >> 5) == 2) ? tanhf(g) : 1.f / (1.f + expf(-g));
    }
    __syncthreads();

    if (t < 32) {
      float iv = gact[t], fv = gact[32 + t], gv = gact[64 + t], ov = gact[96 + t];
      float c = fv * c_reg + iv * gv;
      c_reg = c;
      float h = ov * tanhf(c);
      hbuf[(((step + 1) & 1) * 2 + dir) * Hn + hbase + t] = h;
      hs[(size_t)s * 1024 + dir * Hn + hbase + t] = h;
    }
    // t==0 is in the cell wave: its release drains the wave's stores (vmcnt)
    if (step < SEQn - 1) {
      if (t == 0) {
        __hip_atomic_fetch_add(ctr, 1u, __ATOMIC_RELEASE, __HIP_MEMORY_SCOPE_AGENT);
      }
    }
  }
}

// ---------------------------------------------------------------------------
// Kernel 3: feats = [hs_f|hs_b] @ W_out^T + b_out     (4096 x 34)
// ---------------------------------------------------------------------------
__global__ __launch_bounds__(64) void feats_kernel(
    const float* __restrict__ hs, const float* __restrict__ W_out,
    const float* __restrict__ b_out, float* __restrict__ feats)
{
  const int tq = blockIdx.x;
  const int lane = threadIdx.x;
  const float* hrow = hs + (size_t)tq * 1024;
  float4 hv[4];
#pragma unroll
  for (int i = 0; i < 4; ++i) hv[i] = *(const float4*)(hrow + lane * 16 + i * 4);

  for (int tag = 0; tag < NTAGn; ++tag) {
    const float* wrow = W_out + (size_t)tag * 1024 + lane * 16;
    float s = 0.f;
#pragma unroll
    for (int i = 0; i < 4; ++i) {
      float4 wv = *(const float4*)(wrow + i * 4);
      s += hv[i].x * wv.x + hv[i].y * wv.y + hv[i].z * wv.z + hv[i].w * wv.w;
    }
#pragma unroll
    for (int off = 32; off; off >>= 1) s += __shfl_xor(s, off);
    if (lane == 0) feats[(size_t)tq * NTAGn + tag] = s + b_out[tag];
  }
}

// ---------------------------------------------------------------------------
// Kernel 4: Viterbi forward + backtrack. Single wave; lane = tag.
// ---------------------------------------------------------------------------
__global__ __launch_bounds__(64) void viterbi_kernel(
    const float* __restrict__ feats, const float* __restrict__ logT,
    float* __restrict__ out)
{
  extern __shared__ unsigned char bp[];   // SEQn * NTAGn bytes
  __shared__ float fv_s[36];
  __shared__ float red[36];
  const int lane = threadIdx.x;
  const bool active = lane < NTAGn;

  float Trow[36];
  if (active) {
#pragma unroll
    for (int j = 0; j < NTAGn; ++j) Trow[j] = logT[lane * NTAGn + j];
    Trow[34] = NEGV; Trow[35] = NEGV;
    fv_s[lane] = (lane == START_TAG) ? 0.f : NEGV;
  }
  if (lane == 0) { fv_s[34] = NEGV; fv_s[35] = NEGV; }
  __syncthreads();

  float ft = active ? feats[lane] : 0.f;
  for (int tv = 0; tv < SEQn; ++tv) {
    float best = -3.4e38f; int bj = 0;
    float ftn = 0.f;
    if (active) {
      float sc[36];
#pragma unroll
      for (int q = 0; q < 9; ++q) {
        float4 f4 = *(const float4*)&fv_s[q * 4];
        sc[q*4+0] = f4.x + Trow[q*4+0];
        sc[q*4+1] = f4.y + Trow[q*4+1];
        sc[q*4+2] = f4.z + Trow[q*4+2];
        sc[q*4+3] = f4.w + Trow[q*4+3];
      }
      best = sc[0];
#pragma unroll
      for (int j = 1; j < 36; ++j) { if (sc[j] > best) { best = sc[j]; bj = j; } }
      if (tv + 1 < SEQn) ftn = feats[(size_t)(tv + 1) * NTAGn + lane];
    }
    if (active) {
      fv_s[lane] = best + ft;
      bp[tv * NTAGn + lane] = (unsigned char)bj;
    }
    __threadfence_block();
    ft = ftn;
  }

  if (active) red[lane] = fv_s[lane] + logT[STOP_TAG * NTAGn + lane];
  __threadfence_block();
  __syncthreads();
  if (lane == 0) {
    float bestv = -3.4e38f; int bi = 0;
#pragma unroll
    for (int i = 0; i < NTAGn; ++i) { float v = red[i]; if (v > bestv) { bestv = v; bi = i; } }
    out[0] = bestv;
    int tag = bi;
    out[1 + SEQn - 1] = (float)tag;
    for (int tv = SEQn - 1; tv >= 1; --tv) {
      tag = bp[tv * NTAGn + tag];
      out[tv] = (float)tag;
    }
  }
}

// ---------------------------------------------------------------------------
extern "C" void kernel_launch(void* const* d_in, const int* in_sizes, int n_in,
                              void* d_out, int out_size, void* d_ws, size_t ws_size,
                              hipStream_t stream) {
  const int*   sent   = (const int*)d_in[0];
  const float* embed  = (const float*)d_in[1];
  const float* w_ih_f = (const float*)d_in[2];
  const float* w_hh_f = (const float*)d_in[3];
  const float* b_ih_f = (const float*)d_in[4];
  const float* b_hh_f = (const float*)d_in[5];
  const float* w_ih_b = (const float*)d_in[6];
  const float* w_hh_b = (const float*)d_in[7];
  const float* b_ih_b = (const float*)d_in[8];
  const float* b_hh_b = (const float*)d_in[9];
  const float* W_out  = (const float*)d_in[10];
  const float* b_out  = (const float*)d_in[11];
  const float* logT   = (const float*)d_in[12];
  const float* h0     = (const float*)d_in[13];
  const float* c0     = (const float*)d_in[14];
  float* out = (float*)d_out;

  char* ws = (char*)d_ws;
  size_t off = 0;
  float* xg_f  = (float*)(ws + off); off += (size_t)SEQn * G4n * 4;
  float* xg_b  = (float*)(ws + off); off += (size_t)SEQn * G4n * 4;
  float* hs    = (float*)(ws + off); off += (size_t)SEQn * 1024 * 4;
  float* feats = (float*)(ws + off); off += (size_t)SEQn * NTAGn * 4;
  float* hbuf  = (float*)(ws + off); off += 2 * 2 * Hn * 4;
  unsigned* bar = (unsigned*)(ws + off); off += 512;

  hipMemsetAsync(bar, 0, 512, stream);

  dim3 gg(SEQn / 64, G4n / 64);
  xg_gemm_kernel<<<gg, 256, 0, stream>>>(sent, embed, w_ih_f, b_ih_f, b_hh_f, xg_f);
  xg_gemm_kernel<<<gg, 256, 0, stream>>>(sent, embed, w_ih_b, b_ih_b, b_hh_b, xg_b);

  lstm_kernel<<<32, 1024, 0, stream>>>(xg_f, xg_b, w_hh_f, w_hh_b, h0, c0, hs, hbuf, bar);

  feats_kernel<<<SEQn, 64, 0, stream>>>(hs, W_out, b_out, feats);

  static const int dyn_lds = SEQn * NTAGn;   // 139264 bytes
  hipFuncSetAttribute((const void*)viterbi_kernel,
                      hipFuncAttributeMaxDynamicSharedMemorySize, dyn_lds);
  viterbi_kernel<<<1, 64, dyn_lds, stream>>>(feats, logT, out);
}

// Round 3
// 9713.883 us; speedup vs baseline: 1.5881x; 1.4001x over previous
//
#include <hip/hip_runtime.h>
#include <math.h>

#define SEQn 4096
#define EMBn 1024
#define Hn   512
#define G4n  2048
#define NTAGn 34
#define START_TAG 32
#define STOP_TAG 33
#define NEGV (-10000.0f)

typedef unsigned long long ull;

// ---------------------------------------------------------------------------
// Kernel 1: xg = embed[sent] @ W_ih^T + (b_ih + b_hh)
// ---------------------------------------------------------------------------
__global__ __launch_bounds__(256) void xg_gemm_kernel(
    const int* __restrict__ sent, const float* __restrict__ embed,
    const float* __restrict__ W, const float* __restrict__ bia,
    const float* __restrict__ bib, float* __restrict__ C)
{
  __shared__ __align__(16) float As[32][68];
  __shared__ __align__(16) float Bs[32][68];
  const int tid = threadIdx.x;
  const int tx = tid & 15, ty = tid >> 4;
  const int m0 = blockIdx.x * 64, n0 = blockIdx.y * 64;
  const int lr = tid >> 3, lc = tid & 7;

  const float* arow0 = embed + (size_t)sent[m0 + lr] * EMBn;
  const float* arow1 = embed + (size_t)sent[m0 + 32 + lr] * EMBn;
  const float* brow0 = W + (size_t)(n0 + lr) * EMBn;
  const float* brow1 = W + (size_t)(n0 + 32 + lr) * EMBn;

  float acc[4][4] = {};

  for (int kt = 0; kt < EMBn; kt += 32) {
    float4 a0 = *(const float4*)(arow0 + kt + lc * 4);
    float4 a1 = *(const float4*)(arow1 + kt + lc * 4);
    float4 b0 = *(const float4*)(brow0 + kt + lc * 4);
    float4 b1 = *(const float4*)(brow1 + kt + lc * 4);
    __syncthreads();
    As[lc*4+0][lr] = a0.x; As[lc*4+1][lr] = a0.y; As[lc*4+2][lr] = a0.z; As[lc*4+3][lr] = a0.w;
    As[lc*4+0][32+lr] = a1.x; As[lc*4+1][32+lr] = a1.y; As[lc*4+2][32+lr] = a1.z; As[lc*4+3][32+lr] = a1.w;
    Bs[lc*4+0][lr] = b0.x; Bs[lc*4+1][lr] = b0.y; Bs[lc*4+2][lr] = b0.z; Bs[lc*4+3][lr] = b0.w;
    Bs[lc*4+0][32+lr] = b1.x; Bs[lc*4+1][32+lr] = b1.y; Bs[lc*4+2][32+lr] = b1.z; Bs[lc*4+3][32+lr] = b1.w;
    __syncthreads();
#pragma unroll
    for (int kk = 0; kk < 32; ++kk) {
      float4 av = *(const float4*)&As[kk][ty * 4];
      float4 bv = *(const float4*)&Bs[kk][tx * 4];
      acc[0][0] += av.x * bv.x; acc[0][1] += av.x * bv.y; acc[0][2] += av.x * bv.z; acc[0][3] += av.x * bv.w;
      acc[1][0] += av.y * bv.x; acc[1][1] += av.y * bv.y; acc[1][2] += av.y * bv.z; acc[1][3] += av.y * bv.w;
      acc[2][0] += av.z * bv.x; acc[2][1] += av.z * bv.y; acc[2][2] += av.z * bv.z; acc[2][3] += av.z * bv.w;
      acc[3][0] += av.w * bv.x; acc[3][1] += av.w * bv.y; acc[3][2] += av.w * bv.z; acc[3][3] += av.w * bv.w;
    }
  }
#pragma unroll
  for (int i = 0; i < 4; ++i) {
    int m = m0 + ty * 4 + i;
#pragma unroll
    for (int j = 0; j < 4; ++j) {
      int n = n0 + tx * 4 + j;
      C[(size_t)m * G4n + n] = acc[i][j] + bia[n] + bib[n];
    }
  }
}

// ---------------------------------------------------------------------------
// Kernel 2: persistent bidirectional LSTM, v3 — barrier-free.
// 32 blocks x 1024 threads; blocks 0..15 fwd, 16..31 bwd; block owns 32 h.
// h exchange: tag-stamped 8B atomics hpair[dir][slot=step&3][512] =
// (tag<<32)|bits(h). Consumers poll the data directly (payload in the poll
// load — ONE round trip, no flag indirection, no arrival serialization).
// Waves 8..15 poll (1 slot/lane, parallel); wave 0 runs the gate tail.
// ---------------------------------------------------------------------------
__global__ __launch_bounds__(1024) void lstm_kernel(
    const float* __restrict__ xg_f, const float* __restrict__ xg_b,
    const float* __restrict__ w_hh_f, const float* __restrict__ w_hh_b,
    const float* __restrict__ h0, const float* __restrict__ c0,
    float* __restrict__ hs, ull* __restrict__ hpair)
{
  const int b = blockIdx.x;
  const int dir = b >> 4;
  const int blk = b & 15;
  const int hbase = blk * 32;
  const float* W  = dir ? w_hh_b : w_hh_f;
  const float* xg = dir ? xg_b : xg_f;
  ull* pairs = hpair + (size_t)dir * 4 * Hn;   // [slot][512]

  const int t = threadIdx.x;
  const int w = t >> 6;       // wave id; wave w owns h-segment [w*32, w*32+32)
  const int l = t & 63;       // lane; local gate rows {l, l+64}

  // local row r: gate gi=r>>5, elem idx=r&31 -> global gate row gi*512+hbase+idx
  const int R0 = ((l) >> 5) * Hn + hbase + (l & 31);
  const int R1 = ((l + 64) >> 5) * Hn + hbase + ((l + 64) & 31);
  float4 wreg[16];
  {
    const float* wr0 = W + (size_t)R0 * Hn + w * 32;
    const float* wr1 = W + (size_t)R1 * Hn + w * 32;
#pragma unroll
    for (int jj = 0; jj < 8; ++jj) {
      wreg[jj]     = *(const float4*)(wr0 + jj * 4);
      wreg[8 + jj] = *(const float4*)(wr1 + jj * 4);
    }
  }

  __shared__ __align__(16) float h_lds[Hn];
  __shared__ float part[16 * 130];   // [wave][row], stride 130

  float c_reg = 0.f;
  if (t < 32) c_reg = c0[dir * Hn + hbase + t];

  for (int k = 0; k < SEQn; ++k) {
    const int s = dir ? (SEQn - 1 - k) : k;

    // wave 0 prefetches its xg pair (latency hidden under poll wait)
    float xgv0 = 0.f, xgv1 = 0.f;
    if (w == 0) {
      xgv0 = xg[(size_t)s * G4n + R0];
      xgv1 = xg[(size_t)s * G4n + R1];
    }

    // waves 8..15 obtain h^k (tagged pairs; or h0 at k==0)
    if (t >= 512) {
      const int t0 = t - 512;
      float hv;
      if (k == 0) {
        hv = h0[dir * Hn + t0];
      } else {
        ull* p = pairs + (size_t)(k & 3) * Hn + t0;
        ull v;
        do {
          v = __hip_atomic_load(p, __ATOMIC_RELAXED, __HIP_MEMORY_SCOPE_AGENT);
        } while ((unsigned)(v >> 32) != (unsigned)k);
        hv = __uint_as_float((unsigned)v);
      }
      h_lds[t0] = hv;
    }
    __syncthreads();

    // dot: wave-uniform h segment (broadcast LDS reads), 2 rows per lane
    float a0 = 0.f, a1 = 0.f;
    const float* hseg = h_lds + w * 32;
#pragma unroll
    for (int jj = 0; jj < 8; ++jj) {
      float4 hv = *(const float4*)(hseg + jj * 4);
      float4 wa = wreg[jj], wb = wreg[8 + jj];
      a0 += wa.x * hv.x + wa.y * hv.y + wa.z * hv.z + wa.w * hv.w;
      a1 += wb.x * hv.x + wb.y * hv.y + wb.z * hv.z + wb.w * hv.w;
    }
    part[w * 130 + l] = a0;
    part[w * 130 + 64 + l] = a1;
    __syncthreads();

    // single-wave tail: reduce, activations, cell update, publish
    if (w == 0) {
      float g0 = xgv0, g1 = xgv1;
#pragma unroll
      for (int ww = 0; ww < 16; ++ww) {
        g0 += part[ww * 130 + l];
        g1 += part[ww * 130 + 64 + l];
      }
      // rows l (l<32: i, else f) -> sigmoid; rows l+64 (l<32: g -> tanh, else o -> sigmoid)
      float e0 = __expf(-g0);
      float act0 = 1.f / (1.f + e0);
      float z = (l < 32) ? 2.f * g1 : g1;
      float e1 = __expf(-z);
      float sg = 1.f / (1.f + e1);
      float act1 = (l < 32) ? (2.f * sg - 1.f) : sg;

      float p0 = __shfl_xor(act0, 32);   // lane e<32 gets f(e)
      float p1 = __shfl_xor(act1, 32);   // lane e<32 gets o(e)
      if (l < 32) {
        float iv = act0, gv = act1, fv = p0, ov = p1;
        float c = fv * c_reg + iv * gv;
        c_reg = c;
        float e2 = __expf(-2.f * c);
        float th = (1.f - e2) / (1.f + e2);
        float h = ov * th;
        hs[(size_t)s * 1024 + dir * Hn + hbase + l] = h;
        ull pv = ((ull)(unsigned)(k + 1) << 32) | (ull)__float_as_uint(h);
        __hip_atomic_store(pairs + (size_t)((k + 1) & 3) * Hn + hbase + l, pv,
                           __ATOMIC_RELAXED, __HIP_MEMORY_SCOPE_AGENT);
      }
    }
    // no barrier needed: next-iteration h_lds writes are gated by the top
    // __syncthreads (pollers) and tag availability (own slice published last).
  }
}

// ---------------------------------------------------------------------------
// Kernel 3: feats = [hs_f|hs_b] @ W_out^T + b_out     (4096 x 34)
// ---------------------------------------------------------------------------
__global__ __launch_bounds__(64) void feats_kernel(
    const float* __restrict__ hs, const float* __restrict__ W_out,
    const float* __restrict__ b_out, float* __restrict__ feats)
{
  const int tq = blockIdx.x;
  const int lane = threadIdx.x;
  const float* hrow = hs + (size_t)tq * 1024;
  float4 hv[4];
#pragma unroll
  for (int i = 0; i < 4; ++i) hv[i] = *(const float4*)(hrow + lane * 16 + i * 4);

  for (int tag = 0; tag < NTAGn; ++tag) {
    const float* wrow = W_out + (size_t)tag * 1024 + lane * 16;
    float s = 0.f;
#pragma unroll
    for (int i = 0; i < 4; ++i) {
      float4 wv = *(const float4*)(wrow + i * 4);
      s += hv[i].x * wv.x + hv[i].y * wv.y + hv[i].z * wv.z + hv[i].w * wv.w;
    }
#pragma unroll
    for (int off = 32; off; off >>= 1) s += __shfl_xor(s, off);
    if (lane == 0) feats[(size_t)tq * NTAGn + tag] = s + b_out[tag];
  }
}

// ---------------------------------------------------------------------------
// Kernel 4: Viterbi forward + backtrack. Single wave; lane = tag.
// ---------------------------------------------------------------------------
__global__ __launch_bounds__(64) void viterbi_kernel(
    const float* __restrict__ feats, const float* __restrict__ logT,
    float* __restrict__ out)
{
  extern __shared__ unsigned char bp[];   // SEQn * NTAGn bytes
  __shared__ float fv_s[36];
  __shared__ float red[36];
  const int lane = threadIdx.x;
  const bool active = lane < NTAGn;

  float Trow[36];
  if (active) {
#pragma unroll
    for (int j = 0; j < NTAGn; ++j) Trow[j] = logT[lane * NTAGn + j];
    Trow[34] = NEGV; Trow[35] = NEGV;
    fv_s[lane] = (lane == START_TAG) ? 0.f : NEGV;
  }
  if (lane == 0) { fv_s[34] = NEGV; fv_s[35] = NEGV; }
  __syncthreads();

  float ft = active ? feats[lane] : 0.f;
  for (int tv = 0; tv < SEQn; ++tv) {
    float best = -3.4e38f; int bj = 0;
    float ftn = 0.f;
    if (active) {
      float sc[36];
#pragma unroll
      for (int q = 0; q < 9; ++q) {
        float4 f4 = *(const float4*)&fv_s[q * 4];
        sc[q*4+0] = f4.x + Trow[q*4+0];
        sc[q*4+1] = f4.y + Trow[q*4+1];
        sc[q*4+2] = f4.z + Trow[q*4+2];
        sc[q*4+3] = f4.w + Trow[q*4+3];
      }
      best = sc[0];
#pragma unroll
      for (int j = 1; j < 36; ++j) { if (sc[j] > best) { best = sc[j]; bj = j; } }
      if (tv + 1 < SEQn) ftn = feats[(size_t)(tv + 1) * NTAGn + lane];
    }
    if (active) {
      fv_s[lane] = best + ft;
      bp[tv * NTAGn + lane] = (unsigned char)bj;
    }
    __threadfence_block();
    ft = ftn;
  }

  if (active) red[lane] = fv_s[lane] + logT[STOP_TAG * NTAGn + lane];
  __threadfence_block();
  __syncthreads();
  if (lane == 0) {
    float bestv = -3.4e38f; int bi = 0;
#pragma unroll
    for (int i = 0; i < NTAGn; ++i) { float v = red[i]; if (v > bestv) { bestv = v; bi = i; } }
    out[0] = bestv;
    int tag = bi;
    out[1 + SEQn - 1] = (float)tag;
    for (int tv = SEQn - 1; tv >= 1; --tv) {
      tag = bp[tv * NTAGn + tag];
      out[tv] = (float)tag;
    }
  }
}

// ---------------------------------------------------------------------------
extern "C" void kernel_launch(void* const* d_in, const int* in_sizes, int n_in,
                              void* d_out, int out_size, void* d_ws, size_t ws_size,
                              hipStream_t stream) {
  const int*   sent   = (const int*)d_in[0];
  const float* embed  = (const float*)d_in[1];
  const float* w_ih_f = (const float*)d_in[2];
  const float* w_hh_f = (const float*)d_in[3];
  const float* b_ih_f = (const float*)d_in[4];
  const float* b_hh_f = (const float*)d_in[5];
  const float* w_ih_b = (const float*)d_in[6];
  const float* w_hh_b = (const float*)d_in[7];
  const float* b_ih_b = (const float*)d_in[8];
  const float* b_hh_b = (const float*)d_in[9];
  const float* W_out  = (const float*)d_in[10];
  const float* b_out  = (const float*)d_in[11];
  const float* logT   = (const float*)d_in[12];
  const float* h0     = (const float*)d_in[13];
  const float* c0     = (const float*)d_in[14];
  float* out = (float*)d_out;

  char* ws = (char*)d_ws;
  size_t off = 0;
  float* xg_f  = (float*)(ws + off); off += (size_t)SEQn * G4n * 4;
  float* xg_b  = (float*)(ws + off); off += (size_t)SEQn * G4n * 4;
  float* hs    = (float*)(ws + off); off += (size_t)SEQn * 1024 * 4;
  float* feats = (float*)(ws + off); off += (size_t)SEQn * NTAGn * 4;
  ull*   hpair = (ull*)(ws + off);   off += 2 * 4 * Hn * 8;   // 32 KiB

  hipMemsetAsync(hpair, 0, 2 * 4 * Hn * 8, stream);

  dim3 gg(SEQn / 64, G4n / 64);
  xg_gemm_kernel<<<gg, 256, 0, stream>>>(sent, embed, w_ih_f, b_ih_f, b_hh_f, xg_f);
  xg_gemm_kernel<<<gg, 256, 0, stream>>>(sent, embed, w_ih_b, b_ih_b, b_hh_b, xg_b);

  lstm_kernel<<<32, 1024, 0, stream>>>(xg_f, xg_b, w_hh_f, w_hh_b, h0, c0, hs, hpair);

  feats_kernel<<<SEQn, 64, 0, stream>>>(hs, W_out, b_out, feats);

  static const int dyn_lds = SEQn * NTAGn;   // 139264 bytes
  hipFuncSetAttribute((const void*)viterbi_kernel,
                      hipFuncAttributeMaxDynamicSharedMemorySize, dyn_lds);
  viterbi_kernel<<<1, 64, dyn_lds, stream>>>(feats, logT, out);
}

// Round 4
// 9334.510 us; speedup vs baseline: 1.6527x; 1.0406x over previous
//
#include <hip/hip_runtime.h>
#include <math.h>

#define SEQn 4096
#define EMBn 1024
#define Hn   512
#define G4n  2048
#define NTAGn 34
#define START_TAG 32
#define STOP_TAG 33
#define NEGV (-10000.0f)

typedef unsigned long long ull;

// ---------------------------------------------------------------------------
// Kernel 1: xg = embed[sent] @ W_ih^T + (b_ih + b_hh)
// 64x64 tile, K-tile 32, fp32, software-pipelined global loads.
// ---------------------------------------------------------------------------
__global__ __launch_bounds__(256) void xg_gemm_kernel(
    const int* __restrict__ sent, const float* __restrict__ embed,
    const float* __restrict__ W, const float* __restrict__ bia,
    const float* __restrict__ bib, float* __restrict__ C)
{
  __shared__ __align__(16) float As[32][68];
  __shared__ __align__(16) float Bs[32][68];
  const int tid = threadIdx.x;
  const int tx = tid & 15, ty = tid >> 4;
  const int m0 = blockIdx.x * 64, n0 = blockIdx.y * 64;
  const int lr = tid >> 3, lc = tid & 7;

  const float* arow0 = embed + (size_t)sent[m0 + lr] * EMBn;
  const float* arow1 = embed + (size_t)sent[m0 + 32 + lr] * EMBn;
  const float* brow0 = W + (size_t)(n0 + lr) * EMBn;
  const float* brow1 = W + (size_t)(n0 + 32 + lr) * EMBn;

  float acc[4][4] = {};

  // prologue loads (kt = 0)
  float4 a0 = *(const float4*)(arow0 + lc * 4);
  float4 a1 = *(const float4*)(arow1 + lc * 4);
  float4 b0 = *(const float4*)(brow0 + lc * 4);
  float4 b1 = *(const float4*)(brow1 + lc * 4);

  for (int kt = 0; kt < EMBn; kt += 32) {
    __syncthreads();
    As[lc*4+0][lr] = a0.x; As[lc*4+1][lr] = a0.y; As[lc*4+2][lr] = a0.z; As[lc*4+3][lr] = a0.w;
    As[lc*4+0][32+lr] = a1.x; As[lc*4+1][32+lr] = a1.y; As[lc*4+2][32+lr] = a1.z; As[lc*4+3][32+lr] = a1.w;
    Bs[lc*4+0][lr] = b0.x; Bs[lc*4+1][lr] = b0.y; Bs[lc*4+2][lr] = b0.z; Bs[lc*4+3][lr] = b0.w;
    Bs[lc*4+0][32+lr] = b1.x; Bs[lc*4+1][32+lr] = b1.y; Bs[lc*4+2][32+lr] = b1.z; Bs[lc*4+3][32+lr] = b1.w;
    __syncthreads();
    if (kt + 32 < EMBn) {           // prefetch next K-tile (overlaps compute)
      a0 = *(const float4*)(arow0 + kt + 32 + lc * 4);
      a1 = *(const float4*)(arow1 + kt + 32 + lc * 4);
      b0 = *(const float4*)(brow0 + kt + 32 + lc * 4);
      b1 = *(const float4*)(brow1 + kt + 32 + lc * 4);
    }
#pragma unroll
    for (int kk = 0; kk < 32; ++kk) {
      float4 av = *(const float4*)&As[kk][ty * 4];
      float4 bv = *(const float4*)&Bs[kk][tx * 4];
      acc[0][0] += av.x * bv.x; acc[0][1] += av.x * bv.y; acc[0][2] += av.x * bv.z; acc[0][3] += av.x * bv.w;
      acc[1][0] += av.y * bv.x; acc[1][1] += av.y * bv.y; acc[1][2] += av.y * bv.z; acc[1][3] += av.y * bv.w;
      acc[2][0] += av.z * bv.x; acc[2][1] += av.z * bv.y; acc[2][2] += av.z * bv.z; acc[2][3] += av.z * bv.w;
      acc[3][0] += av.w * bv.x; acc[3][1] += av.w * bv.y; acc[3][2] += av.w * bv.z; acc[3][3] += av.w * bv.w;
    }
  }
#pragma unroll
  for (int i = 0; i < 4; ++i) {
    int m = m0 + ty * 4 + i;
#pragma unroll
    for (int j = 0; j < 4; ++j) {
      int n = n0 + tx * 4 + j;
      C[(size_t)m * G4n + n] = acc[i][j] + bia[n] + bib[n];
    }
  }
}

// ---------------------------------------------------------------------------
// Kernel 2: persistent bidirectional LSTM, v4 — wave-owns-segment.
// 32 blocks x 1024 threads; blocks 0..15 fwd, 16..31 bwd; block owns 32 h.
// Wave w polls ONLY its own h-segment (32 tagged 8B pairs) into wave-private
// LDS: no poller handoff, no barrier between arrival and dot. Tail wave =
// wave 'blk' (its segment is produced locally -> zero poll). part is
// parity-double-buffered -> ONE __syncthreads per step. xg prefetched one
// full step ahead (it streams from HBM/LLC).
// ---------------------------------------------------------------------------
__global__ __launch_bounds__(1024) void lstm_kernel(
    const float* __restrict__ xg_f, const float* __restrict__ xg_b,
    const float* __restrict__ w_hh_f, const float* __restrict__ w_hh_b,
    const float* __restrict__ h0, const float* __restrict__ c0,
    float* __restrict__ hs, ull* __restrict__ hpair)
{
  const int b = blockIdx.x;
  const int dir = b >> 4;
  const int blk = b & 15;
  const int hbase = blk * 32;
  const float* W  = dir ? w_hh_b : w_hh_f;
  const float* xg = dir ? xg_b : xg_f;
  ull* pairs = hpair + (size_t)dir * 4 * Hn;   // [slot][512]

  const int t = threadIdx.x;
  const int w = t >> 6;        // wave id; wave w owns h-segment [w*32, w*32+32)
  const int l = t & 63;        // lane; local gate rows {l, l+64}
  const bool isTW = (w == blk);   // tail wave: its h-segment is local

  // local row r: gate gi=r>>5, elem idx=r&31 -> global gate row gi*512+hbase+idx
  const int R0 = (l >> 5) * Hn + hbase + (l & 31);            // rows 0..63   (i|f)
  const int R1 = ((l + 64) >> 5) * Hn + hbase + (l & 31);     // rows 64..127 (g|o)
  float4 wreg[16];
  {
    const float* wr0 = W + (size_t)R0 * Hn + w * 32;
    const float* wr1 = W + (size_t)R1 * Hn + w * 32;
#pragma unroll
    for (int jj = 0; jj < 8; ++jj) {
      wreg[jj]     = *(const float4*)(wr0 + jj * 4);
      wreg[8 + jj] = *(const float4*)(wr1 + jj * 4);
    }
  }

  __shared__ __align__(16) float h_lds[Hn];          // wave-private segments
  __shared__ float part[2][16 * 130];                // [parity][wave][row]

  if (isTW) __builtin_amdgcn_s_setprio(1);

  float c_reg = 0.f;
  float xg_cur0 = 0.f, xg_cur1 = 0.f, xg_nxt0 = 0.f, xg_nxt1 = 0.f;
  if (isTW) {
    if (l < 32) c_reg = c0[dir * Hn + hbase + l];
    const int s0 = dir ? (SEQn - 1) : 0;
    xg_cur0 = xg[(size_t)s0 * G4n + R0];
    xg_cur1 = xg[(size_t)s0 * G4n + R1];
  }
  // k = 0: every wave loads its own segment of h0
  if (l < 32) h_lds[w * 32 + l] = h0[dir * Hn + w * 32 + l];

  for (int k = 0; k < SEQn; ++k) {
    const int par = k & 1;
    const int s = dir ? (SEQn - 1 - k) : k;

    // TW: prefetch xg for NEXT step (full-step distance covers HBM latency)
    if (isTW && (k + 1 < SEQn)) {
      const int s1 = dir ? (SEQn - 2 - k) : (k + 1);
      xg_nxt0 = xg[(size_t)s1 * G4n + R0];
      xg_nxt1 = xg[(size_t)s1 * G4n + R1];
    }

    // non-tail waves: poll own segment's tagged pairs (k >= 1)
    if (!isTW && k > 0) {
      if (l < 32) {
        ull* p = pairs + (size_t)(k & 3) * Hn + w * 32 + l;
        ull v;
        do {
          v = __hip_atomic_load(p, __ATOMIC_RELAXED, __HIP_MEMORY_SCOPE_AGENT);
        } while ((unsigned)(v >> 32) != (unsigned)k);
        h_lds[w * 32 + l] = __uint_as_float((unsigned)v);
      }
    }
    // intra-wave lgkmcnt ordering makes the writes visible to the reads below

    // dot: wave-uniform broadcast reads of own segment, 2 rows per lane
    float a0 = 0.f, a1 = 0.f;
    {
      const float* hseg = h_lds + w * 32;
#pragma unroll
      for (int jj = 0; jj < 8; ++jj) {
        float4 hv = *(const float4*)(hseg + jj * 4);
        float4 wa = wreg[jj], wb = wreg[8 + jj];
        a0 += wa.x * hv.x + wa.y * hv.y + wa.z * hv.z + wa.w * hv.w;
        a1 += wb.x * hv.x + wb.y * hv.y + wb.z * hv.z + wb.w * hv.w;
      }
    }
    part[par][w * 130 + l] = a0;
    part[par][w * 130 + 64 + l] = a1;
    __syncthreads();   // the ONLY barrier per step

    // tail: reduce 16 partials, activations, cell update, publish
    if (isTW) {
      float g0 = xg_cur0, g1 = xg_cur1;
#pragma unroll
      for (int ww = 0; ww < 16; ++ww) {
        g0 += part[par][ww * 130 + l];
        g1 += part[par][ww * 130 + 64 + l];
      }
      // rows l: i (l<32) / f ; rows l+64: g (l<32, tanh) / o
      float e0 = __expf(-g0);
      float act0 = 1.f / (1.f + e0);
      float z = (l < 32) ? 2.f * g1 : g1;
      float e1 = __expf(-z);
      float sg = 1.f / (1.f + e1);
      float act1 = (l < 32) ? (2.f * sg - 1.f) : sg;

      float p0 = __shfl_xor(act0, 32);   // lane e<32 gets f(e)
      float p1 = __shfl_xor(act1, 32);   // lane e<32 gets o(e)
      if (l < 32) {
        float iv = act0, gv = act1, fv = p0, ov = p1;
        float c = fv * c_reg + iv * gv;
        c_reg = c;
        float e2 = __expf(-2.f * c);
        float h = ov * (1.f - e2) / (1.f + e2);
        hs[(size_t)s * 1024 + dir * Hn + hbase + l] = h;
        h_lds[hbase + l] = h;            // own segment for next step's dot
        if (k + 1 < SEQn) {
          ull pv = ((ull)(unsigned)(k + 1) << 32) | (ull)__float_as_uint(h);
          __hip_atomic_store(pairs + (size_t)((k + 1) & 3) * Hn + hbase + l, pv,
                             __ATOMIC_RELAXED, __HIP_MEMORY_SCOPE_AGENT);
        }
      }
      xg_cur0 = xg_nxt0; xg_cur1 = xg_nxt1;
    }
  }
}

// ---------------------------------------------------------------------------
// Kernel 3: feats = [hs_f|hs_b] @ W_out^T + b_out     (4096 x 34)
// ---------------------------------------------------------------------------
__global__ __launch_bounds__(64) void feats_kernel(
    const float* __restrict__ hs, const float* __restrict__ W_out,
    const float* __restrict__ b_out, float* __restrict__ feats)
{
  const int tq = blockIdx.x;
  const int lane = threadIdx.x;
  const float* hrow = hs + (size_t)tq * 1024;
  float4 hv[4];
#pragma unroll
  for (int i = 0; i < 4; ++i) hv[i] = *(const float4*)(hrow + lane * 16 + i * 4);

  for (int tag = 0; tag < NTAGn; ++tag) {
    const float* wrow = W_out + (size_t)tag * 1024 + lane * 16;
    float s = 0.f;
#pragma unroll
    for (int i = 0; i < 4; ++i) {
      float4 wv = *(const float4*)(wrow + i * 4);
      s += hv[i].x * wv.x + hv[i].y * wv.y + hv[i].z * wv.z + hv[i].w * wv.w;
    }
#pragma unroll
    for (int off = 32; off; off >>= 1) s += __shfl_xor(s, off);
    if (lane == 0) feats[(size_t)tq * NTAGn + tag] = s + b_out[tag];
  }
}

// ---------------------------------------------------------------------------
// Kernel 4: Viterbi forward + backtrack. Single wave; lane = tag.
// ---------------------------------------------------------------------------
__global__ __launch_bounds__(64) void viterbi_kernel(
    const float* __restrict__ feats, const float* __restrict__ logT,
    float* __restrict__ out)
{
  extern __shared__ unsigned char bp[];   // SEQn * NTAGn bytes
  __shared__ float fv_s[36];
  __shared__ float red[36];
  const int lane = threadIdx.x;
  const bool active = lane < NTAGn;

  float Trow[36];
  if (active) {
#pragma unroll
    for (int j = 0; j < NTAGn; ++j) Trow[j] = logT[lane * NTAGn + j];
    Trow[34] = NEGV; Trow[35] = NEGV;
    fv_s[lane] = (lane == START_TAG) ? 0.f : NEGV;
  }
  if (lane == 0) { fv_s[34] = NEGV; fv_s[35] = NEGV; }
  __syncthreads();

  float ft = active ? feats[lane] : 0.f;
  for (int tv = 0; tv < SEQn; ++tv) {
    float best = -3.4e38f; int bj = 0;
    float ftn = 0.f;
    if (active) {
      float sc[36];
#pragma unroll
      for (int q = 0; q < 9; ++q) {
        float4 f4 = *(const float4*)&fv_s[q * 4];
        sc[q*4+0] = f4.x + Trow[q*4+0];
        sc[q*4+1] = f4.y + Trow[q*4+1];
        sc[q*4+2] = f4.z + Trow[q*4+2];
        sc[q*4+3] = f4.w + Trow[q*4+3];
      }
      best = sc[0];
#pragma unroll
      for (int j = 1; j < 36; ++j) { if (sc[j] > best) { best = sc[j]; bj = j; } }
      if (tv + 1 < SEQn) ftn = feats[(size_t)(tv + 1) * NTAGn + lane];
    }
    if (active) {
      fv_s[lane] = best + ft;
      bp[tv * NTAGn + lane] = (unsigned char)bj;
    }
    __threadfence_block();
    ft = ftn;
  }

  if (active) red[lane] = fv_s[lane] + logT[STOP_TAG * NTAGn + lane];
  __threadfence_block();
  __syncthreads();
  if (lane == 0) {
    float bestv = -3.4e38f; int bi = 0;
#pragma unroll
    for (int i = 0; i < NTAGn; ++i) { float v = red[i]; if (v > bestv) { bestv = v; bi = i; } }
    out[0] = bestv;
    int tag = bi;
    out[1 + SEQn - 1] = (float)tag;
    for (int tv = SEQn - 1; tv >= 1; --tv) {
      tag = bp[tv * NTAGn + tag];
      out[tv] = (float)tag;
    }
  }
}

// ---------------------------------------------------------------------------
extern "C" void kernel_launch(void* const* d_in, const int* in_sizes, int n_in,
                              void* d_out, int out_size, void* d_ws, size_t ws_size,
                              hipStream_t stream) {
  const int*   sent   = (const int*)d_in[0];
  const float* embed  = (const float*)d_in[1];
  const float* w_ih_f = (const float*)d_in[2];
  const float* w_hh_f = (const float*)d_in[3];
  const float* b_ih_f = (const float*)d_in[4];
  const float* b_hh_f = (const float*)d_in[5];
  const float* w_ih_b = (const float*)d_in[6];
  const float* w_hh_b = (const float*)d_in[7];
  const float* b_ih_b = (const float*)d_in[8];
  const float* b_hh_b = (const float*)d_in[9];
  const float* W_out  = (const float*)d_in[10];
  const float* b_out  = (const float*)d_in[11];
  const float* logT   = (const float*)d_in[12];
  const float* h0     = (const float*)d_in[13];
  const float* c0     = (const float*)d_in[14];
  float* out = (float*)d_out;

  char* ws = (char*)d_ws;
  size_t off = 0;
  float* xg_f  = (float*)(ws + off); off += (size_t)SEQn * G4n * 4;
  float* xg_b  = (float*)(ws + off); off += (size_t)SEQn * G4n * 4;
  float* hs    = (float*)(ws + off); off += (size_t)SEQn * 1024 * 4;
  float* feats = (float*)(ws + off); off += (size_t)SEQn * NTAGn * 4;
  ull*   hpair = (ull*)(ws + off);   off += 2 * 4 * Hn * 8;   // 32 KiB

  // clear tags every launch (graph replays must not see stale tags)
  hipMemsetAsync(hpair, 0, 2 * 4 * Hn * 8, stream);

  dim3 gg(SEQn / 64, G4n / 64);
  xg_gemm_kernel<<<gg, 256, 0, stream>>>(sent, embed, w_ih_f, b_ih_f, b_hh_f, xg_f);
  xg_gemm_kernel<<<gg, 256, 0, stream>>>(sent, embed, w_ih_b, b_ih_b, b_hh_b, xg_b);

  lstm_kernel<<<32, 1024, 0, stream>>>(xg_f, xg_b, w_hh_f, w_hh_b, h0, c0, hs, hpair);

  feats_kernel<<<SEQn, 64, 0, stream>>>(hs, W_out, b_out, feats);

  static const int dyn_lds = SEQn * NTAGn;   // 139264 bytes
  hipFuncSetAttribute((const void*)viterbi_kernel,
                      hipFuncAttributeMaxDynamicSharedMemorySize, dyn_lds);
  viterbi_kernel<<<1, 64, dyn_lds, stream>>>(feats, logT, out);
}

// Round 5
// 9267.796 us; speedup vs baseline: 1.6646x; 1.0072x over previous
//
#include <hip/hip_runtime.h>
#include <math.h>

#define SEQn 4096
#define EMBn 1024
#define Hn   512
#define G4n  2048
#define NTAGn 34
#define START_TAG 32
#define STOP_TAG 33
#define NEGV (-10000.0f)

typedef unsigned long long ull;

// ---------------------------------------------------------------------------
// Kernel 1: xg = embed[sent] @ W_ih^T + (b_ih + b_hh)
// 64x64 tile, K-tile 32, fp32, software-pipelined global loads.
// ---------------------------------------------------------------------------
__global__ __launch_bounds__(256) void xg_gemm_kernel(
    const int* __restrict__ sent, const float* __restrict__ embed,
    const float* __restrict__ W, const float* __restrict__ bia,
    const float* __restrict__ bib, float* __restrict__ C)
{
  __shared__ __align__(16) float As[32][68];
  __shared__ __align__(16) float Bs[32][68];
  const int tid = threadIdx.x;
  const int tx = tid & 15, ty = tid >> 4;
  const int m0 = blockIdx.x * 64, n0 = blockIdx.y * 64;
  const int lr = tid >> 3, lc = tid & 7;

  const float* arow0 = embed + (size_t)sent[m0 + lr] * EMBn;
  const float* arow1 = embed + (size_t)sent[m0 + 32 + lr] * EMBn;
  const float* brow0 = W + (size_t)(n0 + lr) * EMBn;
  const float* brow1 = W + (size_t)(n0 + 32 + lr) * EMBn;

  float acc[4][4] = {};

  float4 a0 = *(const float4*)(arow0 + lc * 4);
  float4 a1 = *(const float4*)(arow1 + lc * 4);
  float4 b0 = *(const float4*)(brow0 + lc * 4);
  float4 b1 = *(const float4*)(brow1 + lc * 4);

  for (int kt = 0; kt < EMBn; kt += 32) {
    __syncthreads();
    As[lc*4+0][lr] = a0.x; As[lc*4+1][lr] = a0.y; As[lc*4+2][lr] = a0.z; As[lc*4+3][lr] = a0.w;
    As[lc*4+0][32+lr] = a1.x; As[lc*4+1][32+lr] = a1.y; As[lc*4+2][32+lr] = a1.z; As[lc*4+3][32+lr] = a1.w;
    Bs[lc*4+0][lr] = b0.x; Bs[lc*4+1][lr] = b0.y; Bs[lc*4+2][lr] = b0.z; Bs[lc*4+3][lr] = b0.w;
    Bs[lc*4+0][32+lr] = b1.x; Bs[lc*4+1][32+lr] = b1.y; Bs[lc*4+2][32+lr] = b1.z; Bs[lc*4+3][32+lr] = b1.w;
    __syncthreads();
    if (kt + 32 < EMBn) {
      a0 = *(const float4*)(arow0 + kt + 32 + lc * 4);
      a1 = *(const float4*)(arow1 + kt + 32 + lc * 4);
      b0 = *(const float4*)(brow0 + kt + 32 + lc * 4);
      b1 = *(const float4*)(brow1 + kt + 32 + lc * 4);
    }
#pragma unroll
    for (int kk = 0; kk < 32; ++kk) {
      float4 av = *(const float4*)&As[kk][ty * 4];
      float4 bv = *(const float4*)&Bs[kk][tx * 4];
      acc[0][0] += av.x * bv.x; acc[0][1] += av.x * bv.y; acc[0][2] += av.x * bv.z; acc[0][3] += av.x * bv.w;
      acc[1][0] += av.y * bv.x; acc[1][1] += av.y * bv.y; acc[1][2] += av.y * bv.z; acc[1][3] += av.y * bv.w;
      acc[2][0] += av.z * bv.x; acc[2][1] += av.z * bv.y; acc[2][2] += av.z * bv.z; acc[2][3] += av.z * bv.w;
      acc[3][0] += av.w * bv.x; acc[3][1] += av.w * bv.y; acc[3][2] += av.w * bv.z; acc[3][3] += av.w * bv.w;
    }
  }
#pragma unroll
  for (int i = 0; i < 4; ++i) {
    int m = m0 + ty * 4 + i;
#pragma unroll
    for (int j = 0; j < 4; ++j) {
      int n = n0 + tx * 4 + j;
      C[(size_t)m * G4n + n] = acc[i][j] + bia[n] + bib[n];
    }
  }
}

// ---------------------------------------------------------------------------
// L2-coherent 8B load (bypasses L1 via sc0, served by this XCD's L2).
// ---------------------------------------------------------------------------
__device__ __forceinline__ ull load_l2(const ull* p) {
  ull v;
  asm volatile("global_load_dwordx2 %0, %1, off sc0\n\t"
               "s_waitcnt vmcnt(0)"
               : "=v"(v) : "v"(p) : "memory");
  return v;
}

// ---------------------------------------------------------------------------
// Kernel 2: persistent bidirectional LSTM, v5 — XCD-local exchange.
// 128 blocks launched; only bid%8==0 (fwd, rank bid/8) and bid%8==1 (bwd)
// are active -> under round-robin dispatch each direction's 16 blocks share
// ONE XCD, so the h exchange stays in that XCD's L2 (fast path). Dual
// publish keeps correctness mapping-independent: plain 8B store polled with
// sc0 loads (L2, fast) + agent-scope atomic via LLC (slow, always correct).
// Tags are exact-match per step and payloads are deterministic, so stale
// fast-path hits are benign.
// ---------------------------------------------------------------------------
__global__ __launch_bounds__(1024) void lstm_kernel(
    const float* __restrict__ xg_f, const float* __restrict__ xg_b,
    const float* __restrict__ w_hh_f, const float* __restrict__ w_hh_b,
    const float* __restrict__ h0, const float* __restrict__ c0,
    float* __restrict__ hs, ull* __restrict__ hslow, ull* __restrict__ hfast)
{
  const int bid = blockIdx.x;
  if ((bid & 7) >= 2) return;     // inactive placement blocks exit at once
  const int dir = bid & 7;        // 0 = fwd (XCD0), 1 = bwd (XCD1) if %8 holds
  const int blk = bid >> 3;       // 0..15
  const int hbase = blk * 32;
  const float* W  = dir ? w_hh_b : w_hh_f;
  const float* xg = dir ? xg_b : xg_f;
  ull* slow_d = hslow + (size_t)dir * 4 * Hn;   // [slot][512]
  ull* fast_d = hfast + (size_t)dir * 4 * Hn;

  const int t = threadIdx.x;
  const int w = t >> 6;        // wave id; wave w owns h-segment [w*32, w*32+32)
  const int l = t & 63;        // lane; local gate rows {l, l+64}
  const bool isTW = (w == blk);   // tail wave: its h-segment is local

  const int R0 = (l >> 5) * Hn + hbase + (l & 31);            // rows 0..63   (i|f)
  const int R1 = ((l + 64) >> 5) * Hn + hbase + (l & 31);     // rows 64..127 (g|o)
  float4 wreg[16];
  {
    const float* wr0 = W + (size_t)R0 * Hn + w * 32;
    const float* wr1 = W + (size_t)R1 * Hn + w * 32;
#pragma unroll
    for (int jj = 0; jj < 8; ++jj) {
      wreg[jj]     = *(const float4*)(wr0 + jj * 4);
      wreg[8 + jj] = *(const float4*)(wr1 + jj * 4);
    }
  }

  __shared__ __align__(16) float h_lds[Hn];          // wave-private segments
  __shared__ float part[2][16 * 130];                // [parity][wave][row]

  if (isTW) __builtin_amdgcn_s_setprio(1);

  float c_reg = 0.f;
  float xg_cur0 = 0.f, xg_cur1 = 0.f, xg_nxt0 = 0.f, xg_nxt1 = 0.f;
  if (isTW) {
    if (l < 32) c_reg = c0[dir * Hn + hbase + l];
    const int s0 = dir ? (SEQn - 1) : 0;
    xg_cur0 = xg[(size_t)s0 * G4n + R0];
    xg_cur1 = xg[(size_t)s0 * G4n + R1];
  }
  if (l < 32) h_lds[w * 32 + l] = h0[dir * Hn + w * 32 + l];

  for (int k = 0; k < SEQn; ++k) {
    const int par = k & 1;
    const int s = dir ? (SEQn - 1 - k) : k;

    // TW: prefetch xg for NEXT step (full-step distance covers HBM latency)
    if (isTW && (k + 1 < SEQn)) {
      const int s1 = dir ? (SEQn - 2 - k) : (k + 1);
      xg_nxt0 = xg[(size_t)s1 * G4n + R0];
      xg_nxt1 = xg[(size_t)s1 * G4n + R1];
    }

    // non-tail waves: dual-poll own segment (fast L2 path, then LLC path)
    if (!isTW && k > 0) {
      if (l < 32) {
        const size_t idx = (size_t)(k & 3) * Hn + w * 32 + l;
        const ull* fp = fast_d + idx;
        ull* sp = slow_d + idx;
        ull v;
        for (;;) {
          v = load_l2(fp);
          if ((unsigned)(v >> 32) == (unsigned)k) break;
          v = __hip_atomic_load(sp, __ATOMIC_RELAXED, __HIP_MEMORY_SCOPE_AGENT);
          if ((unsigned)(v >> 32) == (unsigned)k) break;
        }
        h_lds[w * 32 + l] = __uint_as_float((unsigned)v);
      }
    }
    // intra-wave lgkmcnt ordering makes the writes visible to the reads below

    // dot: wave-uniform broadcast reads of own segment, 2 rows per lane
    float a0 = 0.f, a1 = 0.f;
    {
      const float* hseg = h_lds + w * 32;
#pragma unroll
      for (int jj = 0; jj < 8; ++jj) {
        float4 hv = *(const float4*)(hseg + jj * 4);
        float4 wa = wreg[jj], wb = wreg[8 + jj];
        a0 += wa.x * hv.x + wa.y * hv.y + wa.z * hv.z + wa.w * hv.w;
        a1 += wb.x * hv.x + wb.y * hv.y + wb.z * hv.z + wb.w * hv.w;
      }
    }
    part[par][w * 130 + l] = a0;
    part[par][w * 130 + 64 + l] = a1;
    __syncthreads();   // the ONLY barrier per step

    // tail: reduce 16 partials, activations, cell update, publish
    if (isTW) {
      float g0 = xg_cur0, g1 = xg_cur1;
#pragma unroll
      for (int ww = 0; ww < 16; ++ww) {
        g0 += part[par][ww * 130 + l];
        g1 += part[par][ww * 130 + 64 + l];
      }
      float e0 = __expf(-g0);
      float act0 = 1.f / (1.f + e0);
      float z = (l < 32) ? 2.f * g1 : g1;
      float e1 = __expf(-z);
      float sg = 1.f / (1.f + e1);
      float act1 = (l < 32) ? (2.f * sg - 1.f) : sg;

      float p0 = __shfl_xor(act0, 32);   // lane e<32 gets f(e)
      float p1 = __shfl_xor(act1, 32);   // lane e<32 gets o(e)
      if (l < 32) {
        float iv = act0, gv = act1, fv = p0, ov = p1;
        float c = fv * c_reg + iv * gv;
        c_reg = c;
        float e2 = __expf(-2.f * c);
        float h = ov * (1.f - e2) / (1.f + e2);
        hs[(size_t)s * 1024 + dir * Hn + hbase + l] = h;
        h_lds[hbase + l] = h;            // own segment for next step's dot
        if (k + 1 < SEQn) {
          ull pv = ((ull)(unsigned)(k + 1) << 32) | (ull)__float_as_uint(h);
          const size_t pidx = (size_t)((k + 1) & 3) * Hn + hbase + l;
          // fast path: plain store -> this XCD's L2 (no sc bits)
          __hip_atomic_store(fast_d + pidx, pv, __ATOMIC_RELAXED,
                             __HIP_MEMORY_SCOPE_WORKGROUP);
          // slow path: agent scope via LLC (correct for any placement)
          __hip_atomic_store(slow_d + pidx, pv, __ATOMIC_RELAXED,
                             __HIP_MEMORY_SCOPE_AGENT);
        }
      }
      xg_cur0 = xg_nxt0; xg_cur1 = xg_nxt1;
    }
  }
}

// ---------------------------------------------------------------------------
// Kernel 3: feats = [hs_f|hs_b] @ W_out^T + b_out     (4096 x 34)
// ---------------------------------------------------------------------------
__global__ __launch_bounds__(64) void feats_kernel(
    const float* __restrict__ hs, const float* __restrict__ W_out,
    const float* __restrict__ b_out, float* __restrict__ feats)
{
  const int tq = blockIdx.x;
  const int lane = threadIdx.x;
  const float* hrow = hs + (size_t)tq * 1024;
  float4 hv[4];
#pragma unroll
  for (int i = 0; i < 4; ++i) hv[i] = *(const float4*)(hrow + lane * 16 + i * 4);

  for (int tag = 0; tag < NTAGn; ++tag) {
    const float* wrow = W_out + (size_t)tag * 1024 + lane * 16;
    float s = 0.f;
#pragma unroll
    for (int i = 0; i < 4; ++i) {
      float4 wv = *(const float4*)(wrow + i * 4);
      s += hv[i].x * wv.x + hv[i].y * wv.y + hv[i].z * wv.z + hv[i].w * wv.w;
    }
#pragma unroll
    for (int off = 32; off; off >>= 1) s += __shfl_xor(s, off);
    if (lane == 0) feats[(size_t)tq * NTAGn + tag] = s + b_out[tag];
  }
}

// ---------------------------------------------------------------------------
// Kernel 4: Viterbi forward + backtrack. Single wave; lane = tag.
// ---------------------------------------------------------------------------
__global__ __launch_bounds__(64) void viterbi_kernel(
    const float* __restrict__ feats, const float* __restrict__ logT,
    float* __restrict__ out)
{
  extern __shared__ unsigned char bp[];   // SEQn * NTAGn bytes
  __shared__ float fv_s[36];
  __shared__ float red[36];
  const int lane = threadIdx.x;
  const bool active = lane < NTAGn;

  float Trow[36];
  if (active) {
#pragma unroll
    for (int j = 0; j < NTAGn; ++j) Trow[j] = logT[lane * NTAGn + j];
    Trow[34] = NEGV; Trow[35] = NEGV;
    fv_s[lane] = (lane == START_TAG) ? 0.f : NEGV;
  }
  if (lane == 0) { fv_s[34] = NEGV; fv_s[35] = NEGV; }
  __syncthreads();

  float ft = active ? feats[lane] : 0.f;
  for (int tv = 0; tv < SEQn; ++tv) {
    float best = -3.4e38f; int bj = 0;
    float ftn = 0.f;
    if (active) {
      float sc[36];
#pragma unroll
      for (int q = 0; q < 9; ++q) {
        float4 f4 = *(const float4*)&fv_s[q * 4];
        sc[q*4+0] = f4.x + Trow[q*4+0];
        sc[q*4+1] = f4.y + Trow[q*4+1];
        sc[q*4+2] = f4.z + Trow[q*4+2];
        sc[q*4+3] = f4.w + Trow[q*4+3];
      }
      best = sc[0];
#pragma unroll
      for (int j = 1; j < 36; ++j) { if (sc[j] > best) { best = sc[j]; bj = j; } }
      if (tv + 1 < SEQn) ftn = feats[(size_t)(tv + 1) * NTAGn + lane];
    }
    if (active) {
      fv_s[lane] = best + ft;
      bp[tv * NTAGn + lane] = (unsigned char)bj;
    }
    __threadfence_block();
    ft = ftn;
  }

  if (active) red[lane] = fv_s[lane] + logT[STOP_TAG * NTAGn + lane];
  __threadfence_block();
  __syncthreads();
  if (lane == 0) {
    float bestv = -3.4e38f; int bi = 0;
#pragma unroll
    for (int i = 0; i < NTAGn; ++i) { float v = red[i]; if (v > bestv) { bestv = v; bi = i; } }
    out[0] = bestv;
    int tag = bi;
    out[1 + SEQn - 1] = (float)tag;
    for (int tv = SEQn - 1; tv >= 1; --tv) {
      tag = bp[tv * NTAGn + tag];
      out[tv] = (float)tag;
    }
  }
}

// ---------------------------------------------------------------------------
extern "C" void kernel_launch(void* const* d_in, const int* in_sizes, int n_in,
                              void* d_out, int out_size, void* d_ws, size_t ws_size,
                              hipStream_t stream) {
  const int*   sent   = (const int*)d_in[0];
  const float* embed  = (const float*)d_in[1];
  const float* w_ih_f = (const float*)d_in[2];
  const float* w_hh_f = (const float*)d_in[3];
  const float* b_ih_f = (const float*)d_in[4];
  const float* b_hh_f = (const float*)d_in[5];
  const float* w_ih_b = (const float*)d_in[6];
  const float* w_hh_b = (const float*)d_in[7];
  const float* b_ih_b = (const float*)d_in[8];
  const float* b_hh_b = (const float*)d_in[9];
  const float* W_out  = (const float*)d_in[10];
  const float* b_out  = (const float*)d_in[11];
  const float* logT   = (const float*)d_in[12];
  const float* h0     = (const float*)d_in[13];
  const float* c0     = (const float*)d_in[14];
  float* out = (float*)d_out;

  char* ws = (char*)d_ws;
  size_t off = 0;
  float* xg_f  = (float*)(ws + off); off += (size_t)SEQn * G4n * 4;
  float* xg_b  = (float*)(ws + off); off += (size_t)SEQn * G4n * 4;
  float* hs    = (float*)(ws + off); off += (size_t)SEQn * 1024 * 4;
  float* feats = (float*)(ws + off); off += (size_t)SEQn * NTAGn * 4;
  ull*   hslow = (ull*)(ws + off);   off += 2 * 4 * Hn * 8;   // 32 KiB
  ull*   hfast = (ull*)(ws + off);   off += 2 * 4 * Hn * 8;   // 32 KiB

  // clear tags every launch (graph replays must not see live tags)
  hipMemsetAsync(hslow, 0, 2 * 4 * Hn * 8, stream);
  hipMemsetAsync(hfast, 0, 2 * 4 * Hn * 8, stream);

  dim3 gg(SEQn / 64, G4n / 64);
  xg_gemm_kernel<<<gg, 256, 0, stream>>>(sent, embed, w_ih_f, b_ih_f, b_hh_f, xg_f);
  xg_gemm_kernel<<<gg, 256, 0, stream>>>(sent, embed, w_ih_b, b_ih_b, b_hh_b, xg_b);

  lstm_kernel<<<128, 1024, 0, stream>>>(xg_f, xg_b, w_hh_f, w_hh_b, h0, c0, hs,
                                        hslow, hfast);

  feats_kernel<<<SEQn, 64, 0, stream>>>(hs, W_out, b_out, feats);

  static const int dyn_lds = SEQn * NTAGn;   // 139264 bytes
  hipFuncSetAttribute((const void*)viterbi_kernel,
                      hipFuncAttributeMaxDynamicSharedMemorySize, dyn_lds);
  viterbi_kernel<<<1, 64, dyn_lds, stream>>>(feats, logT, out);
}